// Round 5
// baseline (563.600 us; speedup 1.0000x reference)
//
#include <hip/hip_runtime.h>

// voltageNN: 5-layer projected LSTM (H=256, P=1) over T=1000, B=128 + MLP head.
// R5: R4 structure + __launch_bounds__(64, 1).
// R3/R4 showed VGPR_Count pinned at 40 (< the 52 persistent floats the cell
// needs) -- the allocator was targeting 8 waves/SIMD for a 64-thread block and
// re-serialized the phase-structured cell to fit. We have 640 waves on 1024
// SIMDs; occupancy is irrelevant. Declaring 1 wave/EU releases the full VGPR
// budget so phase A(s+1) can issue under phase D(s)'s latency.
// Issue floor: 40 trans x 8cyc + ~86 VALU x 2cyc ~= 490 cyc/step.

#define LAYERS 5
#define TT 1000
#define BATCH 128
#define CH 40            // chunk length (divides TT)
#define NCH (TT / CH)    // 25 chunks

#define LOG2E 1.4426950408889634f

__device__ __forceinline__ float fast_exp2(float x) {
#if __has_builtin(__builtin_amdgcn_exp2f)
  return __builtin_amdgcn_exp2f(x);
#else
  return __exp2f(x);
#endif
}
__device__ __forceinline__ float fast_rcp(float x) {
#if __has_builtin(__builtin_amdgcn_rcpf)
  return __builtin_amdgcn_rcpf(x);
#else
  return 1.0f / x;
#endif
}
// sigmoid for the MLP head (unscaled weights there)
__device__ __forceinline__ float fast_sigmoid(float z) {
  float e = fast_exp2(-LOG2E * z);
  return fast_rcp(1.0f + e);
}

template <int CTRL>
__device__ __forceinline__ float dpp_add(float v) {
  int moved = __builtin_amdgcn_update_dpp(0, __builtin_bit_cast(int, v),
                                          CTRL, 0xF, 0xF, false);
  return v + __builtin_bit_cast(float, moved);
}

// Wave64 total, returned wave-uniform (SGPR via readlane 63).
__device__ __forceinline__ float wave_sum_uniform(float v) {
  v = dpp_add<0x128>(v);  // row_ror:8
  v = dpp_add<0x124>(v);  // row_ror:4
  v = dpp_add<0x122>(v);  // row_ror:2
  v = dpp_add<0x121>(v);  // row_ror:1
  v = dpp_add<0x142>(v);  // row_bcast:15
  v = dpp_add<0x143>(v);  // row_bcast:31
  return __builtin_bit_cast(float, __builtin_amdgcn_readlane(__builtin_bit_cast(int, v), 63));
}

__device__ __forceinline__ float lane_bcast(float v, int s) {
  return __builtin_bit_cast(float, __builtin_amdgcn_readlane(__builtin_bit_cast(int, v), s));
}

__global__ __launch_bounds__(64, 1) void lstm_wave_kernel(
    const float* __restrict__ x,     // [B, T]
    const float* __restrict__ Wih,   // [L, 1024]
    const float* __restrict__ Whh,   // [L, 1024]
    const float* __restrict__ bih,   // [L, 1024]
    const float* __restrict__ bhh,   // [L, 1024]
    const float* __restrict__ Whr,   // [L, 256]
    float* __restrict__ seq,         // [L, B, T] layer outputs (workspace)
    int* __restrict__ flags)         // [L, B] chunk progress counters
{
  const int bid  = blockIdx.x;
  const int l    = bid >> 7;   // bid / 128
  const int b    = bid & 127;  // bid % 128
  const int lane = threadIdx.x;

  // per-lane weights, pre-scaled into the exp2 domain.
  // gate order: 0=i, 1=f, 2=g(tanh), 3=o.  E[g] = exp2(sc*(pre-activation))
  // with sc = -log2e for sigmoid gates, -2log2e for the tanh gate.
  float wix[4][4], whx[4][4], gb[4][4], whr[4], cc[4];
  const int base = l * 1024;
#pragma unroll
  for (int g = 0; g < 4; ++g) {
    const float sc = (g == 2) ? (-2.0f * LOG2E) : (-LOG2E);
#pragma unroll
    for (int k = 0; k < 4; ++k) {
      int j = base + g * 256 + k * 64 + lane;
      wix[g][k] = Wih[j] * sc;
      whx[g][k] = Whh[j] * sc;
      gb[g][k]  = (bih[j] + bhh[j]) * sc;
    }
  }
#pragma unroll
  for (int k = 0; k < 4; ++k) {
    whr[k] = Whr[l * 256 + k * 64 + lane];
    cc[k] = 0.0f;
  }

  const float* in  = (l == 0) ? (x + b * TT) : (seq + ((l - 1) * BATCH + b) * TT);
  float*       out = seq + (l * BATCH + b) * TT;
  int*       my_flag = flags + l * BATCH + b;
  const int* in_flag = (l > 0) ? (flags + (l - 1) * BATCH + b) : (const int*)flags;

  float h = 0.0f;
  for (int c = 0; c < NCH; ++c) {
    if (l > 0) {
      while (__hip_atomic_load(in_flag, __ATOMIC_ACQUIRE,
                               __HIP_MEMORY_SCOPE_AGENT) <= c)
        __builtin_amdgcn_s_sleep(2);
    }
    float xv = 0.0f;
    if (lane < CH) {
      if (l == 0)
        xv = in[c * CH + lane];
      else
        xv = __hip_atomic_load(in + c * CH + lane, __ATOMIC_RELAXED,
                               __HIP_MEMORY_SCOPE_AGENT);
    }

    float outv = 0.0f;
#pragma unroll 2
    for (int s = 0; s < CH; ++s) {
      const float xs = lane_bcast(xv, s);

      // phase A: h-independent part of all 16 pre-activations
      float gx[4][4];
#pragma unroll
      for (int g = 0; g < 4; ++g)
#pragma unroll
        for (int k = 0; k < 4; ++k)
          gx[g][k] = fmaf(xs, wix[g][k], gb[g][k]);

      // phase B+C: one fmaf from h, then exp2 (all 16 independent)
      float E[4][4];
#pragma unroll
      for (int g = 0; g < 4; ++g)
#pragma unroll
        for (int k = 0; k < 4; ++k)
          E[g][k] = fast_exp2(fmaf(h, whx[g][k], gx[g][k]));

      // phase D: gate combines, cell update, projection partial (k's independent)
      float rr[4];
#pragma unroll
      for (int k = 0; k < 4; ++k) {
        float ig = fast_rcp(1.0f + E[0][k]);
        float fg = fast_rcp(1.0f + E[1][k]);
        float gg = fmaf(2.0f, fast_rcp(1.0f + E[2][k]), -1.0f);
        float og = fast_rcp(1.0f + E[3][k]);
        cc[k] = fmaf(fg, cc[k], ig * gg);
        float tE = fast_exp2(cc[k] * (-2.0f * LOG2E));
        float tc = fmaf(2.0f, fast_rcp(1.0f + tE), -1.0f);
        rr[k] = og * tc * whr[k];
      }
      float r = (rr[0] + rr[1]) + (rr[2] + rr[3]);

      h = wave_sum_uniform(r);     // SGPR-uniform h(t)
      if (lane == s) outv = h;
    }

    if (l < 4) {
      if (lane < CH)
        __hip_atomic_store(out + c * CH + lane, outv, __ATOMIC_RELAXED,
                           __HIP_MEMORY_SCOPE_AGENT);
      if (lane == 0)
        __hip_atomic_store(my_flag, c + 1, __ATOMIC_RELEASE,
                           __HIP_MEMORY_SCOPE_AGENT);
    } else {
      if (lane < CH) out[c * CH + lane] = outv;  // consumed by next launch
    }
  }
}

__global__ __launch_bounds__(512) void mlp_head_kernel(
    const float* __restrict__ seq4,  // [B, T] layer-4 outputs
    const float* __restrict__ W1, const float* __restrict__ b1,
    const float* __restrict__ W2, const float* __restrict__ b2,
    const float* __restrict__ W3, const float* __restrict__ b3,
    const float* __restrict__ W4, const float* __restrict__ b4,
    float* __restrict__ out)         // [B]
{
  __shared__ float sx[TT];
  __shared__ float sh[100];
  __shared__ float sh2[100];
  __shared__ float part[3][100];
  __shared__ float red[8];

  const int b = blockIdx.x, tid = threadIdx.x;
  for (int i = tid; i < TT; i += 512) sx[i] = seq4[b * TT + i];
  __syncthreads();

  // phase 1: 4 threads per output; quarter q covers t in [250q, 250q+250)
  const int quarter = tid >> 7;        // 0..3
  const int oid     = tid & 127;       // 0..127
  float myacc = 0.0f;
  if (oid < 100) {
    const float* w  = W1 + oid * TT + quarter * 250;
    const float* xx = sx + quarter * 250;
    float a0 = 0.f, a1 = 0.f;
    for (int t0 = 0; t0 < 250; t0 += 2) {   // float2: 8B-aligned (250*4B = 1000B)
      float2 v = *(const float2*)(w + t0);
      a0 = fmaf(v.x, xx[t0 + 0], a0);
      a1 = fmaf(v.y, xx[t0 + 1], a1);
    }
    myacc = a0 + a1;
    if (quarter > 0) part[quarter - 1][oid] = myacc;
  }
  __syncthreads();
  if (tid < 100)
    sh[tid] = fast_sigmoid(myacc + part[0][tid] + part[1][tid] + part[2][tid] + b1[tid]);
  __syncthreads();

  if (tid < 100) {
    float acc = b2[tid];
    const float* w = W2 + tid * 100;
    for (int k = 0; k < 100; ++k) acc += w[k] * sh[k];
    sh2[tid] = fast_sigmoid(acc);
  }
  __syncthreads();

  if (tid < 100) {
    float acc = b3[tid];
    const float* w = W3 + tid * 100;
    for (int k = 0; k < 100; ++k) acc += w[k] * sh2[k];
    sh[tid] = fmaxf(acc, 0.0f);
  }
  __syncthreads();

  float r = (tid < 100) ? sh[tid] * W4[tid] : 0.0f;
  r = wave_sum_uniform(r);
  if ((tid & 63) == 0) red[tid >> 6] = r;
  __syncthreads();
  if (tid == 0)
    out[b] = ((red[0] + red[1]) + (red[2] + red[3])) +
             ((red[4] + red[5]) + (red[6] + red[7])) + b4[0];
}

extern "C" void kernel_launch(void* const* d_in, const int* in_sizes, int n_in,
                              void* d_out, int out_size, void* d_ws, size_t ws_size,
                              hipStream_t stream) {
  const float* x   = (const float*)d_in[0];
  const float* Wih = (const float*)d_in[1];
  const float* Whh = (const float*)d_in[2];
  const float* bih = (const float*)d_in[3];
  const float* bhh = (const float*)d_in[4];
  const float* Whr = (const float*)d_in[5];
  const float* W1  = (const float*)d_in[6];
  const float* b1  = (const float*)d_in[7];
  const float* W2  = (const float*)d_in[8];
  const float* b2  = (const float*)d_in[9];
  const float* W3  = (const float*)d_in[10];
  const float* b3  = (const float*)d_in[11];
  const float* W4  = (const float*)d_in[12];
  const float* b4  = (const float*)d_in[13];

  float* seq   = (float*)d_ws;                       // [5][128][1000] f32 = 2.56 MB
  int*   flags = (int*)(seq + LAYERS * BATCH * TT);  // [5][128] int

  hipMemsetAsync(flags, 0, LAYERS * BATCH * sizeof(int), stream);
  lstm_wave_kernel<<<LAYERS * BATCH, 64, 0, stream>>>(x, Wih, Whh, bih, bhh, Whr,
                                                      seq, flags);
  mlp_head_kernel<<<BATCH, 512, 0, stream>>>(seq + 4 * BATCH * TT,
                                             W1, b1, W2, b2, W3, b3, W4, b4,
                                             (float*)d_out);
}